// Round 6
// baseline (844.938 us; speedup 1.0000x reference)
//
#include <hip/hip_runtime.h>
#include <hip/hip_bf16.h>
#include <math.h>

#define N_NODESC 100000
#define N_EDGESC 1600000
#define N_GRAPHSC 128
#define IN_DIMC 64
#define HIDC 128
#define OUT_DIMC 16
#define NUM_ITERSC 4
#define GAMMAC 0.1f
#define EPSC 0.1f
#define POOL_CHUNKS 8
#define UPD_NB ((N_NODESC + 63) / 64)

// bucketed CSR build
#define NBUK 98                         // ceil(100000/1024), bucket = dst>>10
#define EPB 4096                        // edges per hist/scatter block
#define NBLK ((N_EDGESC + EPB - 1) / EPB)   // 391
#define NHIST (NBUK * NBLK)             // 38318
#define S1NB ((NHIST + 255) / 256)      // 150

typedef __attribute__((ext_vector_type(8))) short bf16x8;
typedef __attribute__((ext_vector_type(4))) float f32x4;

__device__ __forceinline__ unsigned short f2bf(float f) {
  unsigned int u = __float_as_uint(f);
  unsigned int r = (u + 0x7fffu + ((u >> 16) & 1u)) >> 16;  // RNE
  return (unsigned short)r;
}
__device__ __forceinline__ float bflo(unsigned int u) { return __uint_as_float(u << 16); }
__device__ __forceinline__ float bfhi(unsigned int u) { return __uint_as_float(u & 0xffff0000u); }

// Pack combined update weight into B-fragment order for mfma_f32_16x16x32_bf16.
// MTP[((ct*8+kc)*64+lane)*8+j] = M[k][c], k=kc*32+(lane>>4)*8+j, c=ct*16+(lane&15)
__global__ __launch_bounds__(256) void k_weights_pack(const float* __restrict__ W,
                                                      const float* __restrict__ lin_w,
                                                      unsigned short* __restrict__ MTP) {
  int idx = blockIdx.x * 256 + threadIdx.x;
  if (idx >= 32768) return;
  int j = idx & 7;
  int lane = (idx >> 3) & 63;
  int t = idx >> 9;  // ct*8+kc
  int kc = t & 7, ct = t >> 3;
  int k = kc * 32 + (lane >> 4) * 8 + j;
  int c = ct * 16 + (lane & 15);
  float v;
  if (k < HIDC) v = W[c * HIDC + k] - W[k * HIDC + c] - ((k == c) ? GAMMAC : 0.0f);
  else v = lin_w[c * HIDC + (k - HIDC)];
  MTP[idx] = f2bf(v);
}

// Pack emb_w (K=64) into B-fragment order: EWP[((ct*2+kc)*64+lane)*8+j] = emb_w[c][k]
__global__ __launch_bounds__(256) void k_ew_pack(const float* __restrict__ emb_w,
                                                 unsigned short* __restrict__ EWP) {
  int idx = blockIdx.x * 256 + threadIdx.x;
  if (idx >= 8192) return;
  int j = idx & 7;
  int lane = (idx >> 3) & 63;
  int t = idx >> 9;  // ct*2+kc
  int kc = t & 1, ct = t >> 1;
  int k = kc * 32 + (lane >> 4) * 8 + j;
  int c = ct * 16 + (lane & 15);
  EWP[idx] = f2bf(emb_w[c * IN_DIMC + k]);
}

// h = x @ emb_w.T + emb_b via MFMA; writes fp32 h and bf16 shadow hb
__global__ __launch_bounds__(256) void k_embed_mfma(const float* __restrict__ x,
                                                    const unsigned short* __restrict__ EWP,
                                                    const float* __restrict__ emb_b,
                                                    float* __restrict__ h,
                                                    unsigned short* __restrict__ hb) {
  __shared__ __align__(16) unsigned char Xls[64 * 128];  // 64 rows x 64 bf16, swizzled
  int tid = threadIdx.x;
  int r0 = blockIdx.x * 64;
  for (int i = tid; i < 512; i += 256) {
    int row = i >> 3, ck = i & 7;
    int gr = r0 + row;
    uint4 v = make_uint4(0u, 0u, 0u, 0u);
    if (gr < N_NODESC) {
      const float* xp = x + (size_t)gr * IN_DIMC + ck * 8;
      float4 f0 = *(const float4*)xp;
      float4 f1 = *(const float4*)(xp + 4);
      v.x = (unsigned)f2bf(f0.x) | ((unsigned)f2bf(f0.y) << 16);
      v.y = (unsigned)f2bf(f0.z) | ((unsigned)f2bf(f0.w) << 16);
      v.z = (unsigned)f2bf(f1.x) | ((unsigned)f2bf(f1.y) << 16);
      v.w = (unsigned)f2bf(f1.z) | ((unsigned)f2bf(f1.w) << 16);
    }
    *(uint4*)(Xls + row * 128 + ((ck * 16) ^ ((row & 7) << 4))) = v;
  }
  __syncthreads();
  int lane = tid & 63, w = tid >> 6;
  int m = lane & 15, g = lane >> 4;
  int arow = w * 16 + m;
  bf16x8 a0 = *(const bf16x8*)(Xls + arow * 128 + ((g * 16) ^ ((arow & 7) << 4)));
  bf16x8 a1 = *(const bf16x8*)(Xls + arow * 128 + ((64 + g * 16) ^ ((arow & 7) << 4)));
  f32x4 acc[8];
#pragma unroll
  for (int ct = 0; ct < 8; ++ct) acc[ct] = (f32x4){0.f, 0.f, 0.f, 0.f};
#pragma unroll
  for (int ct = 0; ct < 8; ++ct) {
    bf16x8 b0 = *(const bf16x8*)(EWP + ((size_t)((ct * 2 + 0) * 64 + lane)) * 8);
    bf16x8 b1 = *(const bf16x8*)(EWP + ((size_t)((ct * 2 + 1) * 64 + lane)) * 8);
    acc[ct] = __builtin_amdgcn_mfma_f32_16x16x32_bf16(a0, b0, acc[ct], 0, 0, 0);
    acc[ct] = __builtin_amdgcn_mfma_f32_16x16x32_bf16(a1, b1, acc[ct], 0, 0, 0);
  }
#pragma unroll
  for (int ct = 0; ct < 8; ++ct) {
    int col = ct * 16 + m;
    float bias = emb_b[col];
#pragma unroll
    for (int j = 0; j < 4; ++j) {
      int grow = r0 + w * 16 + g * 4 + j;
      if (grow < N_NODESC) {
        size_t o = (size_t)grow * HIDC + col;
        float val = acc[ct][j] + bias;
        h[o] = val;
        hb[o] = f2bf(val);
      }
    }
  }
}

// ---- bucketed CSR build ----
__global__ __launch_bounds__(256) void k_hist(const int* __restrict__ dst, int* __restrict__ histg) {
  __shared__ int hl[NBUK];
  int tid = threadIdx.x;
  for (int i = tid; i < NBUK; i += 256) hl[i] = 0;
  __syncthreads();
  int base = blockIdx.x * EPB;
  int end = base + EPB;
  if (end > N_EDGESC) end = N_EDGESC;
  for (int e = base + tid; e < end; e += 256) atomicAdd(&hl[dst[e] >> 10], 1);
  __syncthreads();
  for (int i = tid; i < NBUK; i += 256) histg[i * NBLK + blockIdx.x] = hl[i];
}

__global__ __launch_bounds__(256) void k_s1(const int* __restrict__ in, int* __restrict__ bsum) {
  __shared__ int red[256];
  int tid = threadIdx.x;
  int i = blockIdx.x * 256 + tid;
  red[tid] = (i < NHIST) ? in[i] : 0;
  __syncthreads();
#pragma unroll
  for (int off = 128; off > 0; off >>= 1) {
    if (tid < off) red[tid] += red[tid + off];
    __syncthreads();
  }
  if (tid == 0) bsum[blockIdx.x] = red[0];
}

__global__ __launch_bounds__(256) void k_s2(int* __restrict__ bsum, int* __restrict__ boff) {
  __shared__ int buf[256];
  int tid = threadIdx.x;
  int v = (tid < S1NB) ? bsum[tid] : 0;
  buf[tid] = v;
  __syncthreads();
  for (int off = 1; off < 256; off <<= 1) {
    int t = (tid >= off) ? buf[tid - off] : 0;
    __syncthreads();
    buf[tid] += t;
    __syncthreads();
  }
  if (tid < S1NB) boff[tid] = buf[tid] - v;
}

__global__ __launch_bounds__(256) void k_s3(const int* __restrict__ in, const int* __restrict__ boff,
                                            int* __restrict__ out) {
  __shared__ int buf[256];
  int tid = threadIdx.x;
  int i = blockIdx.x * 256 + tid;
  int v = (i < NHIST) ? in[i] : 0;
  buf[tid] = v;
  __syncthreads();
  for (int off = 1; off < 256; off <<= 1) {
    int t = (tid >= off) ? buf[tid - off] : 0;
    __syncthreads();
    buf[tid] += t;
    __syncthreads();
  }
  if (i < NHIST) out[i] = boff[blockIdx.x] + buf[tid] - v;
}

__global__ __launch_bounds__(256) void k_scatter(const int* __restrict__ src, const int* __restrict__ dst,
                                                 const int* __restrict__ hoff, unsigned int* __restrict__ ebuf) {
  __shared__ int cur[NBUK];
  int tid = threadIdx.x;
  for (int i = tid; i < NBUK; i += 256) cur[i] = hoff[i * NBLK + blockIdx.x];
  __syncthreads();
  int base = blockIdx.x * EPB;
  int end = base + EPB;
  if (end > N_EDGESC) end = N_EDGESC;
  for (int e = base + tid; e < end; e += 256) {
    int d = dst[e];
    int bu = d >> 10;
    int pos = atomicAdd(&cur[bu], 1);
    ebuf[pos] = ((unsigned int)(d & 1023) << 17) | (unsigned int)src[e];
  }
}

__global__ __launch_bounds__(256) void k_csr(const unsigned int* __restrict__ ebuf,
                                             const int* __restrict__ hoff,
                                             int* __restrict__ rowptr, int* __restrict__ colidx) {
  __shared__ int lcnt[1024];
  __shared__ int lcur[1024];
  __shared__ int ssum[256];
  int b = blockIdx.x, tid = threadIdx.x;
  int ebeg = hoff[b * NBLK];
  int eend = (b + 1 < NBUK) ? hoff[(b + 1) * NBLK] : N_EDGESC;
  for (int i = tid; i < 1024; i += 256) lcnt[i] = 0;
  __syncthreads();
  for (int e = ebeg + tid; e < eend; e += 256) atomicAdd(&lcnt[ebuf[e] >> 17], 1);
  __syncthreads();
  int c0 = lcnt[tid * 4 + 0], c1 = lcnt[tid * 4 + 1], c2 = lcnt[tid * 4 + 2], c3 = lcnt[tid * 4 + 3];
  int s = c0 + c1 + c2 + c3;
  ssum[tid] = s;
  __syncthreads();
  for (int off = 1; off < 256; off <<= 1) {
    int t = (tid >= off) ? ssum[tid - off] : 0;
    __syncthreads();
    ssum[tid] += t;
    __syncthreads();
  }
  int excl = ssum[tid] - s;
  int node0 = (b << 10) + tid * 4;
  int ex = excl;
  lcur[tid * 4 + 0] = ex; if (node0 + 0 < N_NODESC) rowptr[node0 + 0] = ebeg + ex; ex += c0;
  lcur[tid * 4 + 1] = ex; if (node0 + 1 < N_NODESC) rowptr[node0 + 1] = ebeg + ex; ex += c1;
  lcur[tid * 4 + 2] = ex; if (node0 + 2 < N_NODESC) rowptr[node0 + 2] = ebeg + ex; ex += c2;
  lcur[tid * 4 + 3] = ex; if (node0 + 3 < N_NODESC) rowptr[node0 + 3] = ebeg + ex;
  __syncthreads();
  for (int e = ebeg + tid; e < eend; e += 256) {
    unsigned int u = ebuf[e];
    int pos = atomicAdd(&lcur[u >> 17], 1);
    colidx[ebeg + pos] = (int)(u & 0x1FFFFu);
  }
  if (b == 0 && tid == 0) rowptr[N_NODESC] = N_EDGESC;
}

// fused: gather (from hb_src) + MFMA update; h fp32 in-place, bf16 shadow ping-pong to hb_dst
__global__ __launch_bounds__(256) void k_fused(float* __restrict__ h,
                                               const unsigned short* __restrict__ hb_src,
                                               unsigned short* __restrict__ hb_dst,
                                               const int* __restrict__ rowptr,
                                               const int* __restrict__ colidx,
                                               const unsigned short* __restrict__ MTP,
                                               const float* __restrict__ asym_b) {
  __shared__ __align__(16) unsigned char Als[64 * 512];  // 64 rows x 256 bf16 [hb|agg], swizzled
  int tid = threadIdx.x;
  int r0 = blockIdx.x * 64;
  int lane = tid & 63, w = tid >> 6;
  const unsigned int* hbs32 = (const unsigned int*)hb_src;

  // stage own rows (hb half, chunks 0-15)
  for (int i = tid; i < 1024; i += 256) {
    int row = i >> 4;
    int ck = i & 15;
    int gr = r0 + row;
    uint4 v = make_uint4(0u, 0u, 0u, 0u);
    if (gr < N_NODESC) v = ((const uint4*)(hb_src + (size_t)gr * HIDC))[ck];
    *(uint4*)(Als + row * 512 + ((ck * 16) ^ ((row & 7) << 4))) = v;
  }

  // gather: wave w handles rows w*16..w*16+15; lane owns cols 2*lane, 2*lane+1
  for (int rr = 0; rr < 16; ++rr) {
    int r = w * 16 + rr;
    int node = r0 + r;
    float ax = 0.f, ay = 0.f;
    if (node < N_NODESC) {
      int beg = rowptr[node], end = rowptr[node + 1];
      int e = beg;
      for (; e + 4 <= end; e += 4) {
        int s0 = colidx[e], s1 = colidx[e + 1], s2 = colidx[e + 2], s3 = colidx[e + 3];
        unsigned int u0 = hbs32[(size_t)s0 * 64 + lane];
        unsigned int u1 = hbs32[(size_t)s1 * 64 + lane];
        unsigned int u2 = hbs32[(size_t)s2 * 64 + lane];
        unsigned int u3 = hbs32[(size_t)s3 * 64 + lane];
        ax += (bflo(u0) + bflo(u1)) + (bflo(u2) + bflo(u3));
        ay += (bfhi(u0) + bfhi(u1)) + (bfhi(u2) + bfhi(u3));
      }
      for (; e < end; ++e) {
        unsigned int u0 = hbs32[(size_t)colidx[e] * 64 + lane];
        ax += bflo(u0);
        ay += bfhi(u0);
      }
    }
    unsigned int packed = (unsigned int)f2bf(ax) | ((unsigned int)f2bf(ay) << 16);
    *(unsigned int*)(Als + r * 512 + ((256 + 4 * lane) ^ ((r & 7) << 4))) = packed;
  }
  __syncthreads();

  int m = lane & 15, g = lane >> 4;
  int arow = w * 16 + m;
  bf16x8 a[8];
#pragma unroll
  for (int kc = 0; kc < 8; ++kc) {
    a[kc] = *(const bf16x8*)(Als + arow * 512 + ((kc * 64 + g * 16) ^ ((arow & 7) << 4)));
  }
  f32x4 acc[8];
#pragma unroll
  for (int ct = 0; ct < 8; ++ct) acc[ct] = (f32x4){0.f, 0.f, 0.f, 0.f};
#pragma unroll
  for (int ct = 0; ct < 8; ++ct) {
#pragma unroll
    for (int kc = 0; kc < 8; ++kc) {
      bf16x8 b = *(const bf16x8*)(MTP + ((size_t)((ct * 8 + kc) * 64 + lane)) * 8);
      acc[ct] = __builtin_amdgcn_mfma_f32_16x16x32_bf16(a[kc], b, acc[ct], 0, 0, 0);
    }
  }
#pragma unroll
  for (int ct = 0; ct < 8; ++ct) {
    int col = ct * 16 + m;
    float bias = asym_b[col];
#pragma unroll
    for (int j = 0; j < 4; ++j) {
      int grow = r0 + w * 16 + g * 4 + j;
      if (grow < N_NODESC) {
        size_t o = (size_t)grow * HIDC + col;
        float val = h[o] + EPSC * tanhf(acc[ct][j] + bias);
        h[o] = val;
        hb_dst[o] = f2bf(val);
      }
    }
  }
}

__device__ __forceinline__ int lbound_batch(const int* __restrict__ a, int key) {
  int lo = 0, hi = N_NODESC;
  while (lo < hi) {
    int mid = (lo + hi) >> 1;
    if (a[mid] < key) lo = mid + 1;
    else hi = mid;
  }
  return lo;
}

__global__ __launch_bounds__(128) void k_pool1(const float* __restrict__ h,
                                               const int* __restrict__ batch,
                                               float* __restrict__ part) {
  int g = blockIdx.x / POOL_CHUNKS;
  int j = blockIdx.x % POOL_CHUNKS;
  int c = threadIdx.x;
  int lo = lbound_batch(batch, g);
  int hi = lbound_batch(batch, g + 1);
  int n = hi - lo;
  int ch = (n + POOL_CHUNKS - 1) / POOL_CHUNKS;
  int b = lo + j * ch;
  int e = b + ch;
  if (e > hi) e = hi;
  float s = 0.f, m = -INFINITY;
  for (int i = b; i < e; ++i) {
    float v = h[(size_t)i * HIDC + c];
    s += v;
    m = fmaxf(m, v);
  }
  size_t o = ((size_t)g * POOL_CHUNKS + j) * 256;
  part[o + c] = s;
  part[o + 128 + c] = m;
}

__global__ __launch_bounds__(128) void k_pool2(const float* __restrict__ part,
                                               const int* __restrict__ batch,
                                               float* __restrict__ pool) {
  int g = blockIdx.x;
  int c = threadIdx.x;
  float s = 0.f, m = -INFINITY;
#pragma unroll
  for (int j = 0; j < POOL_CHUNKS; ++j) {
    size_t o = ((size_t)g * POOL_CHUNKS + j) * 256;
    s += part[o + c];
    m = fmaxf(m, part[o + 128 + c]);
  }
  int lo = lbound_batch(batch, g);
  int hi = lbound_batch(batch, g + 1);
  float cntf = (float)(hi - lo);
  pool[g * 384 + c] = s;
  pool[g * 384 + 128 + c] = m;
  pool[g * 384 + 256 + c] = s / fmaxf(cntf, 1.f);
}

__global__ __launch_bounds__(192) void k_mlp1(const float* __restrict__ pool,
                                              const float* __restrict__ r1_w,
                                              const float* __restrict__ r1_b,
                                              float* __restrict__ g1) {
  __shared__ float gv[384];
  int g = blockIdx.x;
  for (int i = threadIdx.x; i < 384; i += 192) gv[i] = pool[g * 384 + i];
  __syncthreads();
  int j = threadIdx.x;
  float acc = r1_b[j];
  const float* wr = r1_w + (size_t)j * 384;
#pragma unroll 4
  for (int k = 0; k < 384; ++k) acc = fmaf(gv[k], wr[k], acc);
  g1[g * 192 + j] = (acc > 0.f) ? acc : 0.01f * acc;
}

__global__ __launch_bounds__(256) void k_mlp2(const float* __restrict__ g1,
                                              const float* __restrict__ r2_w,
                                              const float* __restrict__ r2_b,
                                              float* __restrict__ out) {
  int idx = blockIdx.x * 256 + threadIdx.x;
  if (idx >= N_GRAPHSC * OUT_DIMC) return;
  int g = idx >> 4;
  int o = idx & 15;
  float acc = r2_b[o];
  const float* wr = r2_w + o * 192;
  const float* gr = g1 + g * 192;
  for (int k = 0; k < 192; ++k) acc = fmaf(gr[k], wr[k], acc);
  out[idx] = (acc > 0.f) ? acc : 0.01f * acc;
}

extern "C" void kernel_launch(void* const* d_in, const int* in_sizes, int n_in,
                              void* d_out, int out_size, void* d_ws, size_t ws_size,
                              hipStream_t stream) {
  const float* x      = (const float*)d_in[0];
  const int*   ei     = (const int*)d_in[1];
  const int*   batch  = (const int*)d_in[2];
  const float* emb_w  = (const float*)d_in[3];
  const float* emb_b  = (const float*)d_in[4];
  const float* W      = (const float*)d_in[5];
  const float* asym_b = (const float*)d_in[6];
  const float* lin_w  = (const float*)d_in[7];
  const float* r1_w   = (const float*)d_in[8];
  const float* r1_b   = (const float*)d_in[9];
  const float* r2_w   = (const float*)d_in[10];
  const float* r2_b   = (const float*)d_in[11];
  float* out = (float*)d_out;

  char* ws = (char*)d_ws;
  size_t off = 0;
  auto alloc = [&](size_t bytes) -> char* {
    char* p = ws + off;
    off += (bytes + 255) & ~(size_t)255;
    return p;
  };
  float* h            = (float*)alloc((size_t)N_NODESC * HIDC * 4);           // 51.2 MB
  unsigned short* hbA = (unsigned short*)alloc((size_t)N_NODESC * HIDC * 2);  // 25.6 MB
  unsigned short* hbB = (unsigned short*)alloc((size_t)N_NODESC * HIDC * 2);  // 25.6 MB
  unsigned short* MTP = (unsigned short*)alloc((size_t)32768 * 2);            // 64 KB
  unsigned short* EWP = (unsigned short*)alloc((size_t)8192 * 2);             // 16 KB
  int* rowptr   = (int*)alloc((size_t)(N_NODESC + 1) * 4);
  int* colidx   = (int*)alloc((size_t)N_EDGESC * 4);                // 6.4 MB
  unsigned int* ebuf = (unsigned int*)alloc((size_t)N_EDGESC * 4);  // 6.4 MB
  int* histg    = (int*)alloc((size_t)NHIST * 4);
  int* hoff     = (int*)alloc((size_t)NHIST * 4);
  int* bsum     = (int*)alloc((size_t)S1NB * 4);
  int* boff     = (int*)alloc((size_t)S1NB * 4);
  float* part   = (float*)alloc((size_t)N_GRAPHSC * POOL_CHUNKS * 256 * 4);
  float* pool   = (float*)alloc((size_t)N_GRAPHSC * 3 * HIDC * 4);
  float* g1buf  = (float*)alloc((size_t)N_GRAPHSC * 192 * 4);
  (void)ws_size; (void)in_sizes; (void)n_in; (void)out_size;

  const int* srcv = ei;
  const int* dstv = ei + N_EDGESC;

  k_weights_pack<<<128, 256, 0, stream>>>(W, lin_w, MTP);
  k_ew_pack<<<32, 256, 0, stream>>>(emb_w, EWP);
  k_embed_mfma<<<UPD_NB, 256, 0, stream>>>(x, EWP, emb_b, h, hbA);
  k_hist<<<NBLK, 256, 0, stream>>>(dstv, histg);
  k_s1<<<S1NB, 256, 0, stream>>>(histg, bsum);
  k_s2<<<1, 256, 0, stream>>>(bsum, boff);
  k_s3<<<S1NB, 256, 0, stream>>>(histg, boff, hoff);
  k_scatter<<<NBLK, 256, 0, stream>>>(srcv, dstv, hoff, ebuf);
  k_csr<<<NBUK, 256, 0, stream>>>(ebuf, hoff, rowptr, colidx);
  for (int it = 0; it < NUM_ITERSC; ++it) {
    const unsigned short* hs = (it & 1) ? hbB : hbA;
    unsigned short* hd = (it & 1) ? hbA : hbB;
    k_fused<<<UPD_NB, 256, 0, stream>>>(h, hs, hd, rowptr, colidx, MTP, asym_b);
  }
  k_pool1<<<N_GRAPHSC * POOL_CHUNKS, 128, 0, stream>>>(h, batch, part);
  k_pool2<<<N_GRAPHSC, 128, 0, stream>>>(part, batch, pool);
  k_mlp1<<<N_GRAPHSC, 192, 0, stream>>>(pool, r1_w, r1_b, g1buf);
  k_mlp2<<<(N_GRAPHSC * OUT_DIMC + 255) / 256, 256, 0, stream>>>(g1buf, r2_w, r2_b, out);
}

// Round 7
// 643.709 us; speedup vs baseline: 1.3126x; 1.3126x over previous
//
#include <hip/hip_runtime.h>
#include <hip/hip_bf16.h>
#include <math.h>

#define N_NODESC 100000
#define N_EDGESC 1600000
#define N_GRAPHSC 128
#define IN_DIMC 64
#define HIDC 128
#define OUT_DIMC 16
#define NUM_ITERSC 4
#define GAMMAC 0.1f
#define EPSC 0.1f
#define POOL_CHUNKS 8
#define UPD_NB ((N_NODESC + 63) / 64)

// bucketed CSR build
#define NBUK 98                         // ceil(100000/1024), bucket = dst>>10
#define EPB 4096                        // edges per hist/scatter block
#define NBLK ((N_EDGESC + EPB - 1) / EPB)   // 391
#define NHIST (NBUK * NBLK)             // 38318
#define S1NB ((NHIST + 255) / 256)      // 150

typedef __attribute__((ext_vector_type(8))) short bf16x8;
typedef __attribute__((ext_vector_type(4))) float f32x4;

__device__ __forceinline__ unsigned short f2bf(float f) {
  unsigned int u = __float_as_uint(f);
  unsigned int r = (u + 0x7fffu + ((u >> 16) & 1u)) >> 16;  // RNE
  return (unsigned short)r;
}
__device__ __forceinline__ float bflo(unsigned int u) { return __uint_as_float(u << 16); }
__device__ __forceinline__ float bfhi(unsigned int u) { return __uint_as_float(u & 0xffff0000u); }

__device__ __forceinline__ float tanh_fast(float x) {
  float a = fminf(fabsf(x), 15.0f);
  float e = __expf(2.0f * a);
  float r = (e - 1.0f) / (e + 1.0f);
  return copysignf(r, x);
}

// Pack combined update weight into B-fragment order for mfma_f32_16x16x32_bf16.
// MTP[((ct*8+kc)*64+lane)*8+j] = M[k][c], k=kc*32+(lane>>4)*8+j, c=ct*16+(lane&15)
__global__ __launch_bounds__(256) void k_weights_pack(const float* __restrict__ W,
                                                      const float* __restrict__ lin_w,
                                                      unsigned short* __restrict__ MTP) {
  int idx = blockIdx.x * 256 + threadIdx.x;
  if (idx >= 32768) return;
  int j = idx & 7;
  int lane = (idx >> 3) & 63;
  int t = idx >> 9;  // ct*8+kc
  int kc = t & 7, ct = t >> 3;
  int k = kc * 32 + (lane >> 4) * 8 + j;
  int c = ct * 16 + (lane & 15);
  float v;
  if (k < HIDC) v = W[c * HIDC + k] - W[k * HIDC + c] - ((k == c) ? GAMMAC : 0.0f);
  else v = lin_w[c * HIDC + (k - HIDC)];
  MTP[idx] = f2bf(v);
}

// Pack emb_w (K=64) into B-fragment order: EWP[((ct*2+kc)*64+lane)*8+j] = emb_w[c][k]
__global__ __launch_bounds__(256) void k_ew_pack(const float* __restrict__ emb_w,
                                                 unsigned short* __restrict__ EWP) {
  int idx = blockIdx.x * 256 + threadIdx.x;
  if (idx >= 8192) return;
  int j = idx & 7;
  int lane = (idx >> 3) & 63;
  int t = idx >> 9;  // ct*2+kc
  int kc = t & 1, ct = t >> 1;
  int k = kc * 32 + (lane >> 4) * 8 + j;
  int c = ct * 16 + (lane & 15);
  EWP[idx] = f2bf(emb_w[c * IN_DIMC + k]);
}

// h = x @ emb_w.T + emb_b via MFMA; writes fp32 h and bf16 shadow hb
__global__ __launch_bounds__(256) void k_embed_mfma(const float* __restrict__ x,
                                                    const unsigned short* __restrict__ EWP,
                                                    const float* __restrict__ emb_b,
                                                    float* __restrict__ h,
                                                    unsigned short* __restrict__ hb) {
  __shared__ __align__(16) unsigned char Xls[64 * 128];  // 64 rows x 64 bf16, swizzled
  int tid = threadIdx.x;
  int r0 = blockIdx.x * 64;
  for (int i = tid; i < 512; i += 256) {
    int row = i >> 3, ck = i & 7;
    int gr = r0 + row;
    uint4 v = make_uint4(0u, 0u, 0u, 0u);
    if (gr < N_NODESC) {
      const float* xp = x + (size_t)gr * IN_DIMC + ck * 8;
      float4 f0 = *(const float4*)xp;
      float4 f1 = *(const float4*)(xp + 4);
      v.x = (unsigned)f2bf(f0.x) | ((unsigned)f2bf(f0.y) << 16);
      v.y = (unsigned)f2bf(f0.z) | ((unsigned)f2bf(f0.w) << 16);
      v.z = (unsigned)f2bf(f1.x) | ((unsigned)f2bf(f1.y) << 16);
      v.w = (unsigned)f2bf(f1.z) | ((unsigned)f2bf(f1.w) << 16);
    }
    *(uint4*)(Xls + row * 128 + ((ck * 16) ^ ((row & 7) << 4))) = v;
  }
  __syncthreads();
  int lane = tid & 63, w = tid >> 6;
  int m = lane & 15, g = lane >> 4;
  int arow = w * 16 + m;
  bf16x8 a0 = *(const bf16x8*)(Xls + arow * 128 + ((g * 16) ^ ((arow & 7) << 4)));
  bf16x8 a1 = *(const bf16x8*)(Xls + arow * 128 + ((64 + g * 16) ^ ((arow & 7) << 4)));
  f32x4 acc[8];
#pragma unroll
  for (int ct = 0; ct < 8; ++ct) acc[ct] = (f32x4){0.f, 0.f, 0.f, 0.f};
#pragma unroll
  for (int ct = 0; ct < 8; ++ct) {
    bf16x8 b0 = *(const bf16x8*)(EWP + ((size_t)((ct * 2 + 0) * 64 + lane)) * 8);
    bf16x8 b1 = *(const bf16x8*)(EWP + ((size_t)((ct * 2 + 1) * 64 + lane)) * 8);
    acc[ct] = __builtin_amdgcn_mfma_f32_16x16x32_bf16(a0, b0, acc[ct], 0, 0, 0);
    acc[ct] = __builtin_amdgcn_mfma_f32_16x16x32_bf16(a1, b1, acc[ct], 0, 0, 0);
  }
#pragma unroll
  for (int ct = 0; ct < 8; ++ct) {
    int col = ct * 16 + m;
    float bias = emb_b[col];
#pragma unroll
    for (int j = 0; j < 4; ++j) {
      int grow = r0 + w * 16 + g * 4 + j;
      if (grow < N_NODESC) {
        size_t o = (size_t)grow * HIDC + col;
        float val = acc[ct][j] + bias;
        h[o] = val;
        hb[o] = f2bf(val);
      }
    }
  }
}

// ---- bucketed CSR build ----
__global__ __launch_bounds__(256) void k_hist(const int* __restrict__ dst, int* __restrict__ histg) {
  __shared__ int hl[NBUK];
  int tid = threadIdx.x;
  for (int i = tid; i < NBUK; i += 256) hl[i] = 0;
  __syncthreads();
  int base = blockIdx.x * EPB;
  int end = base + EPB;
  if (end > N_EDGESC) end = N_EDGESC;
  for (int e = base + tid; e < end; e += 256) atomicAdd(&hl[dst[e] >> 10], 1);
  __syncthreads();
  for (int i = tid; i < NBUK; i += 256) histg[i * NBLK + blockIdx.x] = hl[i];
}

__global__ __launch_bounds__(256) void k_s1(const int* __restrict__ in, int* __restrict__ bsum) {
  __shared__ int red[256];
  int tid = threadIdx.x;
  int i = blockIdx.x * 256 + tid;
  red[tid] = (i < NHIST) ? in[i] : 0;
  __syncthreads();
#pragma unroll
  for (int off = 128; off > 0; off >>= 1) {
    if (tid < off) red[tid] += red[tid + off];
    __syncthreads();
  }
  if (tid == 0) bsum[blockIdx.x] = red[0];
}

__global__ __launch_bounds__(256) void k_s2(int* __restrict__ bsum, int* __restrict__ boff) {
  __shared__ int buf[256];
  int tid = threadIdx.x;
  int v = (tid < S1NB) ? bsum[tid] : 0;
  buf[tid] = v;
  __syncthreads();
  for (int off = 1; off < 256; off <<= 1) {
    int t = (tid >= off) ? buf[tid - off] : 0;
    __syncthreads();
    buf[tid] += t;
    __syncthreads();
  }
  if (tid < S1NB) boff[tid] = buf[tid] - v;
}

__global__ __launch_bounds__(256) void k_s3(const int* __restrict__ in, const int* __restrict__ boff,
                                            int* __restrict__ out) {
  __shared__ int buf[256];
  int tid = threadIdx.x;
  int i = blockIdx.x * 256 + tid;
  int v = (i < NHIST) ? in[i] : 0;
  buf[tid] = v;
  __syncthreads();
  for (int off = 1; off < 256; off <<= 1) {
    int t = (tid >= off) ? buf[tid - off] : 0;
    __syncthreads();
    buf[tid] += t;
    __syncthreads();
  }
  if (i < NHIST) out[i] = boff[blockIdx.x] + buf[tid] - v;
}

__global__ __launch_bounds__(256) void k_scatter(const int* __restrict__ src, const int* __restrict__ dst,
                                                 const int* __restrict__ hoff, unsigned int* __restrict__ ebuf) {
  __shared__ int cur[NBUK];
  int tid = threadIdx.x;
  for (int i = tid; i < NBUK; i += 256) cur[i] = hoff[i * NBLK + blockIdx.x];
  __syncthreads();
  int base = blockIdx.x * EPB;
  int end = base + EPB;
  if (end > N_EDGESC) end = N_EDGESC;
  for (int e = base + tid; e < end; e += 256) {
    int d = dst[e];
    int bu = d >> 10;
    int pos = atomicAdd(&cur[bu], 1);
    ebuf[pos] = ((unsigned int)(d & 1023) << 17) | (unsigned int)src[e];
  }
}

__global__ __launch_bounds__(256) void k_csr(const unsigned int* __restrict__ ebuf,
                                             const int* __restrict__ hoff,
                                             int* __restrict__ rowptr, int* __restrict__ colidx) {
  __shared__ int lcnt[1024];
  __shared__ int lcur[1024];
  __shared__ int ssum[256];
  int b = blockIdx.x, tid = threadIdx.x;
  int ebeg = hoff[b * NBLK];
  int eend = (b + 1 < NBUK) ? hoff[(b + 1) * NBLK] : N_EDGESC;
  for (int i = tid; i < 1024; i += 256) lcnt[i] = 0;
  __syncthreads();
  for (int e = ebeg + tid; e < eend; e += 256) atomicAdd(&lcnt[ebuf[e] >> 17], 1);
  __syncthreads();
  int c0 = lcnt[tid * 4 + 0], c1 = lcnt[tid * 4 + 1], c2 = lcnt[tid * 4 + 2], c3 = lcnt[tid * 4 + 3];
  int s = c0 + c1 + c2 + c3;
  ssum[tid] = s;
  __syncthreads();
  for (int off = 1; off < 256; off <<= 1) {
    int t = (tid >= off) ? ssum[tid - off] : 0;
    __syncthreads();
    ssum[tid] += t;
    __syncthreads();
  }
  int excl = ssum[tid] - s;
  int node0 = (b << 10) + tid * 4;
  int ex = excl;
  lcur[tid * 4 + 0] = ex; if (node0 + 0 < N_NODESC) rowptr[node0 + 0] = ebeg + ex; ex += c0;
  lcur[tid * 4 + 1] = ex; if (node0 + 1 < N_NODESC) rowptr[node0 + 1] = ebeg + ex; ex += c1;
  lcur[tid * 4 + 2] = ex; if (node0 + 2 < N_NODESC) rowptr[node0 + 2] = ebeg + ex; ex += c2;
  lcur[tid * 4 + 3] = ex; if (node0 + 3 < N_NODESC) rowptr[node0 + 3] = ebeg + ex;
  __syncthreads();
  for (int e = ebeg + tid; e < eend; e += 256) {
    unsigned int u = ebuf[e];
    int pos = atomicAdd(&lcur[u >> 17], 1);
    colidx[ebeg + pos] = (int)(u & 0x1FFFFu);
  }
  if (b == 0 && tid == 0) rowptr[N_NODESC] = N_EDGESC;
}

// agg over in-edges from bf16 shadow; one wave per node, 2 cols per lane, unroll 4
__global__ __launch_bounds__(256) void k_gather_b(const unsigned int* __restrict__ hb32,
                                                  const int* __restrict__ rowptr,
                                                  const int* __restrict__ colidx,
                                                  unsigned int* __restrict__ aggb32) {
  int node = blockIdx.x * 4 + (threadIdx.x >> 6);
  int lane = threadIdx.x & 63;
  if (node >= N_NODESC) return;
  int beg = rowptr[node];
  int end = rowptr[node + 1];
  float ax = 0.f, ay = 0.f;
  int e = beg;
  for (; e + 4 <= end; e += 4) {
    int s0 = colidx[e], s1 = colidx[e + 1], s2 = colidx[e + 2], s3 = colidx[e + 3];
    unsigned int u0 = hb32[(size_t)s0 * 64 + lane];
    unsigned int u1 = hb32[(size_t)s1 * 64 + lane];
    unsigned int u2 = hb32[(size_t)s2 * 64 + lane];
    unsigned int u3 = hb32[(size_t)s3 * 64 + lane];
    ax += (bflo(u0) + bflo(u1)) + (bflo(u2) + bflo(u3));
    ay += (bfhi(u0) + bfhi(u1)) + (bfhi(u2) + bfhi(u3));
  }
  for (; e < end; ++e) {
    unsigned int u0 = hb32[(size_t)colidx[e] * 64 + lane];
    ax += bflo(u0);
    ay += bfhi(u0);
  }
  aggb32[(size_t)node * 64 + lane] = (unsigned int)f2bf(ax) | ((unsigned int)f2bf(ay) << 16);
}

// conv = [hb|aggb] @ M^T via MFMA bf16 (K=256); h += eps*tanh(conv+b); refresh hb in place.
__global__ __launch_bounds__(256) void k_update_mfma(float* __restrict__ h,
                                                     unsigned short* __restrict__ hb,
                                                     const unsigned short* __restrict__ aggb,
                                                     const unsigned short* __restrict__ MTP,
                                                     const float* __restrict__ asym_b) {
  __shared__ __align__(16) unsigned char Als[64 * 512];
  int tid = threadIdx.x;
  int r0 = blockIdx.x * 64;
  for (int i = tid; i < 2048; i += 256) {
    int row = i >> 5;
    int ck = i & 31;
    int gr = r0 + row;
    uint4 v = make_uint4(0u, 0u, 0u, 0u);
    if (gr < N_NODESC) {
      if (ck < 16) v = ((const uint4*)(hb + (size_t)gr * HIDC))[ck];
      else v = ((const uint4*)(aggb + (size_t)gr * HIDC))[ck - 16];
    }
    *(uint4*)(Als + row * 512 + ((ck * 16) ^ ((row & 7) << 4))) = v;
  }
  __syncthreads();
  int lane = tid & 63, w = tid >> 6;
  int m = lane & 15, g = lane >> 4;
  int arow = w * 16 + m;
  bf16x8 a[8];
#pragma unroll
  for (int kc = 0; kc < 8; ++kc) {
    a[kc] = *(const bf16x8*)(Als + arow * 512 + ((kc * 64 + g * 16) ^ ((arow & 7) << 4)));
  }
  f32x4 acc[8];
#pragma unroll
  for (int ct = 0; ct < 8; ++ct) acc[ct] = (f32x4){0.f, 0.f, 0.f, 0.f};
#pragma unroll
  for (int ct = 0; ct < 8; ++ct) {
#pragma unroll
    for (int kc = 0; kc < 8; ++kc) {
      bf16x8 b = *(const bf16x8*)(MTP + ((size_t)((ct * 8 + kc) * 64 + lane)) * 8);
      acc[ct] = __builtin_amdgcn_mfma_f32_16x16x32_bf16(a[kc], b, acc[ct], 0, 0, 0);
    }
  }
#pragma unroll
  for (int ct = 0; ct < 8; ++ct) {
    int col = ct * 16 + m;
    float bias = asym_b[col];
#pragma unroll
    for (int j = 0; j < 4; ++j) {
      int grow = r0 + w * 16 + g * 4 + j;
      if (grow < N_NODESC) {
        size_t o = (size_t)grow * HIDC + col;
        float val = h[o] + EPSC * tanh_fast(acc[ct][j] + bias);
        h[o] = val;
        hb[o] = f2bf(val);
      }
    }
  }
}

__device__ __forceinline__ int lbound_batch(const int* __restrict__ a, int key) {
  int lo = 0, hi = N_NODESC;
  while (lo < hi) {
    int mid = (lo + hi) >> 1;
    if (a[mid] < key) lo = mid + 1;
    else hi = mid;
  }
  return lo;
}

__global__ __launch_bounds__(128) void k_pool1(const float* __restrict__ h,
                                               const int* __restrict__ batch,
                                               float* __restrict__ part) {
  int g = blockIdx.x / POOL_CHUNKS;
  int j = blockIdx.x % POOL_CHUNKS;
  int c = threadIdx.x;
  int lo = lbound_batch(batch, g);
  int hi = lbound_batch(batch, g + 1);
  int n = hi - lo;
  int ch = (n + POOL_CHUNKS - 1) / POOL_CHUNKS;
  int b = lo + j * ch;
  int e = b + ch;
  if (e > hi) e = hi;
  float s = 0.f, m = -INFINITY;
  for (int i = b; i < e; ++i) {
    float v = h[(size_t)i * HIDC + c];
    s += v;
    m = fmaxf(m, v);
  }
  size_t o = ((size_t)g * POOL_CHUNKS + j) * 256;
  part[o + c] = s;
  part[o + 128 + c] = m;
}

__global__ __launch_bounds__(128) void k_pool2(const float* __restrict__ part,
                                               const int* __restrict__ batch,
                                               float* __restrict__ pool) {
  int g = blockIdx.x;
  int c = threadIdx.x;
  float s = 0.f, m = -INFINITY;
#pragma unroll
  for (int j = 0; j < POOL_CHUNKS; ++j) {
    size_t o = ((size_t)g * POOL_CHUNKS + j) * 256;
    s += part[o + c];
    m = fmaxf(m, part[o + 128 + c]);
  }
  int lo = lbound_batch(batch, g);
  int hi = lbound_batch(batch, g + 1);
  float cntf = (float)(hi - lo);
  pool[g * 384 + c] = s;
  pool[g * 384 + 128 + c] = m;
  pool[g * 384 + 256 + c] = s / fmaxf(cntf, 1.f);
}

__global__ __launch_bounds__(192) void k_mlp1(const float* __restrict__ pool,
                                              const float* __restrict__ r1_w,
                                              const float* __restrict__ r1_b,
                                              float* __restrict__ g1) {
  __shared__ float gv[384];
  int g = blockIdx.x;
  for (int i = threadIdx.x; i < 384; i += 192) gv[i] = pool[g * 384 + i];
  __syncthreads();
  int j = threadIdx.x;
  float acc = r1_b[j];
  const float* wr = r1_w + (size_t)j * 384;
#pragma unroll 4
  for (int k = 0; k < 384; ++k) acc = fmaf(gv[k], wr[k], acc);
  g1[g * 192 + j] = (acc > 0.f) ? acc : 0.01f * acc;
}

__global__ __launch_bounds__(256) void k_mlp2(const float* __restrict__ g1,
                                              const float* __restrict__ r2_w,
                                              const float* __restrict__ r2_b,
                                              float* __restrict__ out) {
  int idx = blockIdx.x * 256 + threadIdx.x;
  if (idx >= N_GRAPHSC * OUT_DIMC) return;
  int g = idx >> 4;
  int o = idx & 15;
  float acc = r2_b[o];
  const float* wr = r2_w + o * 192;
  const float* gr = g1 + g * 192;
  for (int k = 0; k < 192; ++k) acc = fmaf(gr[k], wr[k], acc);
  out[idx] = (acc > 0.f) ? acc : 0.01f * acc;
}

extern "C" void kernel_launch(void* const* d_in, const int* in_sizes, int n_in,
                              void* d_out, int out_size, void* d_ws, size_t ws_size,
                              hipStream_t stream) {
  const float* x      = (const float*)d_in[0];
  const int*   ei     = (const int*)d_in[1];
  const int*   batch  = (const int*)d_in[2];
  const float* emb_w  = (const float*)d_in[3];
  const float* emb_b  = (const float*)d_in[4];
  const float* W      = (const float*)d_in[5];
  const float* asym_b = (const float*)d_in[6];
  const float* lin_w  = (const float*)d_in[7];
  const float* r1_w   = (const float*)d_in[8];
  const float* r1_b   = (const float*)d_in[9];
  const float* r2_w   = (const float*)d_in[10];
  const float* r2_b   = (const float*)d_in[11];
  float* out = (float*)d_out;

  char* ws = (char*)d_ws;
  size_t off = 0;
  auto alloc = [&](size_t bytes) -> char* {
    char* p = ws + off;
    off += (bytes + 255) & ~(size_t)255;
    return p;
  };
  float* h            = (float*)alloc((size_t)N_NODESC * HIDC * 4);           // 51.2 MB
  unsigned short* hb  = (unsigned short*)alloc((size_t)N_NODESC * HIDC * 2);  // 25.6 MB
  unsigned short* ab  = (unsigned short*)alloc((size_t)N_NODESC * HIDC * 2);  // 25.6 MB
  unsigned short* MTP = (unsigned short*)alloc((size_t)32768 * 2);            // 64 KB
  unsigned short* EWP = (unsigned short*)alloc((size_t)8192 * 2);             // 16 KB
  int* rowptr   = (int*)alloc((size_t)(N_NODESC + 1) * 4);
  int* colidx   = (int*)alloc((size_t)N_EDGESC * 4);                // 6.4 MB
  unsigned int* ebuf = (unsigned int*)alloc((size_t)N_EDGESC * 4);  // 6.4 MB
  int* histg    = (int*)alloc((size_t)NHIST * 4);
  int* hoff     = (int*)alloc((size_t)NHIST * 4);
  int* bsum     = (int*)alloc((size_t)S1NB * 4);
  int* boff     = (int*)alloc((size_t)S1NB * 4);
  float* part   = (float*)alloc((size_t)N_GRAPHSC * POOL_CHUNKS * 256 * 4);
  float* pool   = (float*)alloc((size_t)N_GRAPHSC * 3 * HIDC * 4);
  float* g1buf  = (float*)alloc((size_t)N_GRAPHSC * 192 * 4);
  (void)ws_size; (void)in_sizes; (void)n_in; (void)out_size;

  const int* srcv = ei;
  const int* dstv = ei + N_EDGESC;

  k_weights_pack<<<128, 256, 0, stream>>>(W, lin_w, MTP);
  k_ew_pack<<<32, 256, 0, stream>>>(emb_w, EWP);
  k_embed_mfma<<<UPD_NB, 256, 0, stream>>>(x, EWP, emb_b, h, hb);
  k_hist<<<NBLK, 256, 0, stream>>>(dstv, histg);
  k_s1<<<S1NB, 256, 0, stream>>>(histg, bsum);
  k_s2<<<1, 256, 0, stream>>>(bsum, boff);
  k_s3<<<S1NB, 256, 0, stream>>>(histg, boff, hoff);
  k_scatter<<<NBLK, 256, 0, stream>>>(srcv, dstv, hoff, ebuf);
  k_csr<<<NBUK, 256, 0, stream>>>(ebuf, hoff, rowptr, colidx);
  for (int it = 0; it < NUM_ITERSC; ++it) {
    k_gather_b<<<N_NODESC / 4, 256, 0, stream>>>((const unsigned int*)hb, rowptr, colidx,
                                                 (unsigned int*)ab);
    k_update_mfma<<<UPD_NB, 256, 0, stream>>>(h, hb, ab, MTP, asym_b);
  }
  k_pool1<<<N_GRAPHSC * POOL_CHUNKS, 128, 0, stream>>>(h, batch, part);
  k_pool2<<<N_GRAPHSC, 128, 0, stream>>>(part, batch, pool);
  k_mlp1<<<N_GRAPHSC, 192, 0, stream>>>(pool, r1_w, r1_b, g1buf);
  k_mlp2<<<(N_GRAPHSC * OUT_DIMC + 255) / 256, 256, 0, stream>>>(g1buf, r2_w, r2_b, out);
}

// Round 8
// 552.183 us; speedup vs baseline: 1.5302x; 1.1658x over previous
//
#include <hip/hip_runtime.h>
#include <hip/hip_bf16.h>
#include <math.h>

#define N_NODESC 100000
#define N_EDGESC 1600000
#define N_GRAPHSC 128
#define IN_DIMC 64
#define HIDC 128
#define OUT_DIMC 16
#define NUM_ITERSC 4
#define GAMMAC 0.1f
#define EPSC 0.1f
#define POOL_CHUNKS 8
#define UPD_NB ((N_NODESC + 63) / 64)

// bucketed CSR build
#define NBUK 98                         // ceil(100000/1024), bucket = dst>>10
#define EPB 4096                        // edges per hist/scatter block
#define NBLK ((N_EDGESC + EPB - 1) / EPB)   // 391
#define NHIST (NBUK * NBLK)             // 38318
#define S1NB ((NHIST + 255) / 256)      // 150

typedef __attribute__((ext_vector_type(8))) short bf16x8;
typedef __attribute__((ext_vector_type(4))) float f32x4;

__device__ __forceinline__ unsigned short f2bf(float f) {
  unsigned int u = __float_as_uint(f);
  unsigned int r = (u + 0x7fffu + ((u >> 16) & 1u)) >> 16;  // RNE
  return (unsigned short)r;
}
__device__ __forceinline__ float bflo(unsigned int u) { return __uint_as_float(u << 16); }
__device__ __forceinline__ float bfhi(unsigned int u) { return __uint_as_float(u & 0xffff0000u); }

__device__ __forceinline__ float tanh_fast(float x) {
  float a = fminf(fabsf(x), 15.0f);
  float e = __expf(2.0f * a);
  float r = (e - 1.0f) / (e + 1.0f);
  return copysignf(r, x);
}

// Pack combined update weight into B-fragment order for mfma_f32_16x16x32_bf16.
// MTP[((ct*8+kc)*64+lane)*8+j] = M[k][c], k=kc*32+(lane>>4)*8+j, c=ct*16+(lane&15)
__global__ __launch_bounds__(256) void k_weights_pack(const float* __restrict__ W,
                                                      const float* __restrict__ lin_w,
                                                      unsigned short* __restrict__ MTP) {
  int idx = blockIdx.x * 256 + threadIdx.x;
  if (idx >= 32768) return;
  int j = idx & 7;
  int lane = (idx >> 3) & 63;
  int t = idx >> 9;  // ct*8+kc
  int kc = t & 7, ct = t >> 3;
  int k = kc * 32 + (lane >> 4) * 8 + j;
  int c = ct * 16 + (lane & 15);
  float v;
  if (k < HIDC) v = W[c * HIDC + k] - W[k * HIDC + c] - ((k == c) ? GAMMAC : 0.0f);
  else v = lin_w[c * HIDC + (k - HIDC)];
  MTP[idx] = f2bf(v);
}

// Pack emb_w (K=64) into B-fragment order: EWP[((ct*2+kc)*64+lane)*8+j] = emb_w[c][k]
__global__ __launch_bounds__(256) void k_ew_pack(const float* __restrict__ emb_w,
                                                 unsigned short* __restrict__ EWP) {
  int idx = blockIdx.x * 256 + threadIdx.x;
  if (idx >= 8192) return;
  int j = idx & 7;
  int lane = (idx >> 3) & 63;
  int t = idx >> 9;  // ct*2+kc
  int kc = t & 1, ct = t >> 1;
  int k = kc * 32 + (lane >> 4) * 8 + j;
  int c = ct * 16 + (lane & 15);
  EWP[idx] = f2bf(emb_w[c * IN_DIMC + k]);
}

// hb = bf16(x @ emb_w.T + emb_b) via MFMA; hb is the sole state
__global__ __launch_bounds__(256) void k_embed_mfma(const float* __restrict__ x,
                                                    const unsigned short* __restrict__ EWP,
                                                    const float* __restrict__ emb_b,
                                                    unsigned short* __restrict__ hb) {
  __shared__ __align__(16) unsigned char Xls[64 * 128];  // 64 rows x 64 bf16, swizzled
  int tid = threadIdx.x;
  int r0 = blockIdx.x * 64;
  for (int i = tid; i < 512; i += 256) {
    int row = i >> 3, ck = i & 7;
    int gr = r0 + row;
    uint4 v = make_uint4(0u, 0u, 0u, 0u);
    if (gr < N_NODESC) {
      const float* xp = x + (size_t)gr * IN_DIMC + ck * 8;
      float4 f0 = *(const float4*)xp;
      float4 f1 = *(const float4*)(xp + 4);
      v.x = (unsigned)f2bf(f0.x) | ((unsigned)f2bf(f0.y) << 16);
      v.y = (unsigned)f2bf(f0.z) | ((unsigned)f2bf(f0.w) << 16);
      v.z = (unsigned)f2bf(f1.x) | ((unsigned)f2bf(f1.y) << 16);
      v.w = (unsigned)f2bf(f1.z) | ((unsigned)f2bf(f1.w) << 16);
    }
    *(uint4*)(Xls + row * 128 + ((ck * 16) ^ ((row & 7) << 4))) = v;
  }
  __syncthreads();
  int lane = tid & 63, w = tid >> 6;
  int m = lane & 15, g = lane >> 4;
  int arow = w * 16 + m;
  bf16x8 a0 = *(const bf16x8*)(Xls + arow * 128 + ((g * 16) ^ ((arow & 7) << 4)));
  bf16x8 a1 = *(const bf16x8*)(Xls + arow * 128 + ((64 + g * 16) ^ ((arow & 7) << 4)));
  f32x4 acc[8];
#pragma unroll
  for (int ct = 0; ct < 8; ++ct) acc[ct] = (f32x4){0.f, 0.f, 0.f, 0.f};
#pragma unroll
  for (int ct = 0; ct < 8; ++ct) {
    bf16x8 b0 = *(const bf16x8*)(EWP + ((size_t)((ct * 2 + 0) * 64 + lane)) * 8);
    bf16x8 b1 = *(const bf16x8*)(EWP + ((size_t)((ct * 2 + 1) * 64 + lane)) * 8);
    acc[ct] = __builtin_amdgcn_mfma_f32_16x16x32_bf16(a0, b0, acc[ct], 0, 0, 0);
    acc[ct] = __builtin_amdgcn_mfma_f32_16x16x32_bf16(a1, b1, acc[ct], 0, 0, 0);
  }
#pragma unroll
  for (int ct = 0; ct < 8; ++ct) {
    int col = ct * 16 + m;
    float bias = emb_b[col];
#pragma unroll
    for (int j = 0; j < 4; ++j) {
      int grow = r0 + w * 16 + g * 4 + j;
      if (grow < N_NODESC) {
        hb[(size_t)grow * HIDC + col] = f2bf(acc[ct][j] + bias);
      }
    }
  }
}

// ---- bucketed CSR build ----
__global__ __launch_bounds__(256) void k_hist(const int* __restrict__ dst, int* __restrict__ histg) {
  __shared__ int hl[NBUK];
  int tid = threadIdx.x;
  for (int i = tid; i < NBUK; i += 256) hl[i] = 0;
  __syncthreads();
  int base = blockIdx.x * EPB;
  int end = base + EPB;
  if (end > N_EDGESC) end = N_EDGESC;
  for (int e = base + tid; e < end; e += 256) atomicAdd(&hl[dst[e] >> 10], 1);
  __syncthreads();
  for (int i = tid; i < NBUK; i += 256) histg[i * NBLK + blockIdx.x] = hl[i];
}

__global__ __launch_bounds__(256) void k_s1(const int* __restrict__ in, int* __restrict__ bsum) {
  __shared__ int red[256];
  int tid = threadIdx.x;
  int i = blockIdx.x * 256 + tid;
  red[tid] = (i < NHIST) ? in[i] : 0;
  __syncthreads();
#pragma unroll
  for (int off = 128; off > 0; off >>= 1) {
    if (tid < off) red[tid] += red[tid + off];
    __syncthreads();
  }
  if (tid == 0) bsum[blockIdx.x] = red[0];
}

__global__ __launch_bounds__(256) void k_s2(int* __restrict__ bsum, int* __restrict__ boff) {
  __shared__ int buf[256];
  int tid = threadIdx.x;
  int v = (tid < S1NB) ? bsum[tid] : 0;
  buf[tid] = v;
  __syncthreads();
  for (int off = 1; off < 256; off <<= 1) {
    int t = (tid >= off) ? buf[tid - off] : 0;
    __syncthreads();
    buf[tid] += t;
    __syncthreads();
  }
  if (tid < S1NB) boff[tid] = buf[tid] - v;
}

__global__ __launch_bounds__(256) void k_s3(const int* __restrict__ in, const int* __restrict__ boff,
                                            int* __restrict__ out) {
  __shared__ int buf[256];
  int tid = threadIdx.x;
  int i = blockIdx.x * 256 + tid;
  int v = (i < NHIST) ? in[i] : 0;
  buf[tid] = v;
  __syncthreads();
  for (int off = 1; off < 256; off <<= 1) {
    int t = (tid >= off) ? buf[tid - off] : 0;
    __syncthreads();
    buf[tid] += t;
    __syncthreads();
  }
  if (i < NHIST) out[i] = boff[blockIdx.x] + buf[tid] - v;
}

__global__ __launch_bounds__(256) void k_scatter(const int* __restrict__ src, const int* __restrict__ dst,
                                                 const int* __restrict__ hoff, unsigned int* __restrict__ ebuf) {
  __shared__ int cur[NBUK];
  int tid = threadIdx.x;
  for (int i = tid; i < NBUK; i += 256) cur[i] = hoff[i * NBLK + blockIdx.x];
  __syncthreads();
  int base = blockIdx.x * EPB;
  int end = base + EPB;
  if (end > N_EDGESC) end = N_EDGESC;
  for (int e = base + tid; e < end; e += 256) {
    int d = dst[e];
    int bu = d >> 10;
    int pos = atomicAdd(&cur[bu], 1);
    ebuf[pos] = ((unsigned int)(d & 1023) << 17) | (unsigned int)src[e];
  }
}

__global__ __launch_bounds__(256) void k_csr(const unsigned int* __restrict__ ebuf,
                                             const int* __restrict__ hoff,
                                             int* __restrict__ rowptr, int* __restrict__ colidx) {
  __shared__ int lcnt[1024];
  __shared__ int lcur[1024];
  __shared__ int ssum[256];
  int b = blockIdx.x, tid = threadIdx.x;
  int ebeg = hoff[b * NBLK];
  int eend = (b + 1 < NBUK) ? hoff[(b + 1) * NBLK] : N_EDGESC;
  for (int i = tid; i < 1024; i += 256) lcnt[i] = 0;
  __syncthreads();
  for (int e = ebeg + tid; e < eend; e += 256) atomicAdd(&lcnt[ebuf[e] >> 17], 1);
  __syncthreads();
  int c0 = lcnt[tid * 4 + 0], c1 = lcnt[tid * 4 + 1], c2 = lcnt[tid * 4 + 2], c3 = lcnt[tid * 4 + 3];
  int s = c0 + c1 + c2 + c3;
  ssum[tid] = s;
  __syncthreads();
  for (int off = 1; off < 256; off <<= 1) {
    int t = (tid >= off) ? ssum[tid - off] : 0;
    __syncthreads();
    ssum[tid] += t;
    __syncthreads();
  }
  int excl = ssum[tid] - s;
  int node0 = (b << 10) + tid * 4;
  int ex = excl;
  lcur[tid * 4 + 0] = ex; if (node0 + 0 < N_NODESC) rowptr[node0 + 0] = ebeg + ex; ex += c0;
  lcur[tid * 4 + 1] = ex; if (node0 + 1 < N_NODESC) rowptr[node0 + 1] = ebeg + ex; ex += c1;
  lcur[tid * 4 + 2] = ex; if (node0 + 2 < N_NODESC) rowptr[node0 + 2] = ebeg + ex; ex += c2;
  lcur[tid * 4 + 3] = ex; if (node0 + 3 < N_NODESC) rowptr[node0 + 3] = ebeg + ex;
  __syncthreads();
  for (int e = ebeg + tid; e < eend; e += 256) {
    unsigned int u = ebuf[e];
    int pos = atomicAdd(&lcur[u >> 17], 1);
    colidx[ebeg + pos] = (int)(u & 0x1FFFFu);
  }
  if (b == 0 && tid == 0) rowptr[N_NODESC] = N_EDGESC;
}

// agg over in-edges from bf16 shadow; one wave per node, 2 cols per lane, unroll 8
__global__ __launch_bounds__(256) void k_gather_b(const unsigned int* __restrict__ hb32,
                                                  const int* __restrict__ rowptr,
                                                  const int* __restrict__ colidx,
                                                  unsigned int* __restrict__ aggb32) {
  int node = blockIdx.x * 4 + (threadIdx.x >> 6);
  int lane = threadIdx.x & 63;
  if (node >= N_NODESC) return;
  int beg = rowptr[node];
  int end = rowptr[node + 1];
  float ax = 0.f, ay = 0.f;
  int e = beg;
  for (; e + 8 <= end; e += 8) {
    unsigned int u0 = hb32[(size_t)colidx[e + 0] * 64 + lane];
    unsigned int u1 = hb32[(size_t)colidx[e + 1] * 64 + lane];
    unsigned int u2 = hb32[(size_t)colidx[e + 2] * 64 + lane];
    unsigned int u3 = hb32[(size_t)colidx[e + 3] * 64 + lane];
    unsigned int u4 = hb32[(size_t)colidx[e + 4] * 64 + lane];
    unsigned int u5 = hb32[(size_t)colidx[e + 5] * 64 + lane];
    unsigned int u6 = hb32[(size_t)colidx[e + 6] * 64 + lane];
    unsigned int u7 = hb32[(size_t)colidx[e + 7] * 64 + lane];
    ax += ((bflo(u0) + bflo(u1)) + (bflo(u2) + bflo(u3))) +
          ((bflo(u4) + bflo(u5)) + (bflo(u6) + bflo(u7)));
    ay += ((bfhi(u0) + bfhi(u1)) + (bfhi(u2) + bfhi(u3))) +
          ((bfhi(u4) + bfhi(u5)) + (bfhi(u6) + bfhi(u7)));
  }
  for (; e + 2 <= end; e += 2) {
    unsigned int u0 = hb32[(size_t)colidx[e] * 64 + lane];
    unsigned int u1 = hb32[(size_t)colidx[e + 1] * 64 + lane];
    ax += bflo(u0) + bflo(u1);
    ay += bfhi(u0) + bfhi(u1);
  }
  if (e < end) {
    unsigned int u0 = hb32[(size_t)colidx[e] * 64 + lane];
    ax += bflo(u0);
    ay += bfhi(u0);
  }
  aggb32[(size_t)node * 64 + lane] = (unsigned int)f2bf(ax) | ((unsigned int)f2bf(ay) << 16);
}

// conv = [hb|aggb] @ M^T via MFMA bf16 (K=256); hb = bf16(hb + eps*tanh(conv+b)) in place.
// own-row h_old read back from the staged LDS A-tile (no global h master).
__global__ __launch_bounds__(256) void k_update_mfma(unsigned short* __restrict__ hb,
                                                     const unsigned short* __restrict__ aggb,
                                                     const unsigned short* __restrict__ MTP,
                                                     const float* __restrict__ asym_b) {
  __shared__ __align__(16) unsigned char Als[64 * 512];
  int tid = threadIdx.x;
  int r0 = blockIdx.x * 64;
  for (int i = tid; i < 2048; i += 256) {
    int row = i >> 5;
    int ck = i & 31;
    int gr = r0 + row;
    uint4 v = make_uint4(0u, 0u, 0u, 0u);
    if (gr < N_NODESC) {
      if (ck < 16) v = ((const uint4*)(hb + (size_t)gr * HIDC))[ck];
      else v = ((const uint4*)(aggb + (size_t)gr * HIDC))[ck - 16];
    }
    *(uint4*)(Als + row * 512 + ((ck * 16) ^ ((row & 7) << 4))) = v;
  }
  __syncthreads();
  int lane = tid & 63, w = tid >> 6;
  int m = lane & 15, g = lane >> 4;
  int arow = w * 16 + m;
  bf16x8 a[8];
#pragma unroll
  for (int kc = 0; kc < 8; ++kc) {
    a[kc] = *(const bf16x8*)(Als + arow * 512 + ((kc * 64 + g * 16) ^ ((arow & 7) << 4)));
  }
  f32x4 acc[8];
#pragma unroll
  for (int ct = 0; ct < 8; ++ct) acc[ct] = (f32x4){0.f, 0.f, 0.f, 0.f};
#pragma unroll
  for (int ct = 0; ct < 8; ++ct) {
#pragma unroll
    for (int kc = 0; kc < 8; ++kc) {
      bf16x8 b = *(const bf16x8*)(MTP + ((size_t)((ct * 8 + kc) * 64 + lane)) * 8);
      acc[ct] = __builtin_amdgcn_mfma_f32_16x16x32_bf16(a[kc], b, acc[ct], 0, 0, 0);
    }
  }
#pragma unroll
  for (int ct = 0; ct < 8; ++ct) {
    int col = ct * 16 + m;
    float bias = asym_b[col];
    int lb = col * 2;  // byte offset of col within a row's hb half
#pragma unroll
    for (int j = 0; j < 4; ++j) {
      int lrow = w * 16 + g * 4 + j;
      int grow = r0 + lrow;
      if (grow < N_NODESC) {
        int addr = lrow * 512 + (((lb & ~15) ^ ((lrow & 7) << 4)) | (lb & 15));
        unsigned short hu = *(const unsigned short*)(Als + addr);
        float hold = __uint_as_float((unsigned)hu << 16);
        float val = hold + EPSC * tanh_fast(acc[ct][j] + bias);
        hb[(size_t)grow * HIDC + col] = f2bf(val);
      }
    }
  }
}

__device__ __forceinline__ int lbound_batch(const int* __restrict__ a, int key) {
  int lo = 0, hi = N_NODESC;
  while (lo < hi) {
    int mid = (lo + hi) >> 1;
    if (a[mid] < key) lo = mid + 1;
    else hi = mid;
  }
  return lo;
}

__global__ __launch_bounds__(128) void k_pool1(const unsigned short* __restrict__ hb,
                                               const int* __restrict__ batch,
                                               float* __restrict__ part) {
  int g = blockIdx.x / POOL_CHUNKS;
  int j = blockIdx.x % POOL_CHUNKS;
  int c = threadIdx.x;
  int lo = lbound_batch(batch, g);
  int hi = lbound_batch(batch, g + 1);
  int n = hi - lo;
  int ch = (n + POOL_CHUNKS - 1) / POOL_CHUNKS;
  int b = lo + j * ch;
  int e = b + ch;
  if (e > hi) e = hi;
  float s = 0.f, m = -INFINITY;
  for (int i = b; i < e; ++i) {
    unsigned short u = hb[(size_t)i * HIDC + c];
    float v = __uint_as_float((unsigned)u << 16);
    s += v;
    m = fmaxf(m, v);
  }
  size_t o = ((size_t)g * POOL_CHUNKS + j) * 256;
  part[o + c] = s;
  part[o + 128 + c] = m;
}

__global__ __launch_bounds__(128) void k_pool2(const float* __restrict__ part,
                                               const int* __restrict__ batch,
                                               float* __restrict__ pool) {
  int g = blockIdx.x;
  int c = threadIdx.x;
  float s = 0.f, m = -INFINITY;
#pragma unroll
  for (int j = 0; j < POOL_CHUNKS; ++j) {
    size_t o = ((size_t)g * POOL_CHUNKS + j) * 256;
    s += part[o + c];
    m = fmaxf(m, part[o + 128 + c]);
  }
  int lo = lbound_batch(batch, g);
  int hi = lbound_batch(batch, g + 1);
  float cntf = (float)(hi - lo);
  pool[g * 384 + c] = s;
  pool[g * 384 + 128 + c] = m;
  pool[g * 384 + 256 + c] = s / fmaxf(cntf, 1.f);
}

__global__ __launch_bounds__(192) void k_mlp1(const float* __restrict__ pool,
                                              const float* __restrict__ r1_w,
                                              const float* __restrict__ r1_b,
                                              float* __restrict__ g1) {
  __shared__ float gv[384];
  int g = blockIdx.x;
  for (int i = threadIdx.x; i < 384; i += 192) gv[i] = pool[g * 384 + i];
  __syncthreads();
  int j = threadIdx.x;
  float acc = r1_b[j];
  const float* wr = r1_w + (size_t)j * 384;
#pragma unroll 4
  for (int k = 0; k < 384; ++k) acc = fmaf(gv[k], wr[k], acc);
  g1[g * 192 + j] = (acc > 0.f) ? acc : 0.01f * acc;
}

__global__ __launch_bounds__(256) void k_mlp2(const float* __restrict__ g1,
                                              const float* __restrict__ r2_w,
                                              const float* __restrict__ r2_b,
                                              float* __restrict__ out) {
  int idx = blockIdx.x * 256 + threadIdx.x;
  if (idx >= N_GRAPHSC * OUT_DIMC) return;
  int g = idx >> 4;
  int o = idx & 15;
  float acc = r2_b[o];
  const float* wr = r2_w + o * 192;
  const float* gr = g1 + g * 192;
  for (int k = 0; k < 192; ++k) acc = fmaf(gr[k], wr[k], acc);
  out[idx] = (acc > 0.f) ? acc : 0.01f * acc;
}

extern "C" void kernel_launch(void* const* d_in, const int* in_sizes, int n_in,
                              void* d_out, int out_size, void* d_ws, size_t ws_size,
                              hipStream_t stream) {
  const float* x      = (const float*)d_in[0];
  const int*   ei     = (const int*)d_in[1];
  const int*   batch  = (const int*)d_in[2];
  const float* emb_w  = (const float*)d_in[3];
  const float* emb_b  = (const float*)d_in[4];
  const float* W      = (const float*)d_in[5];
  const float* asym_b = (const float*)d_in[6];
  const float* lin_w  = (const float*)d_in[7];
  const float* r1_w   = (const float*)d_in[8];
  const float* r1_b   = (const float*)d_in[9];
  const float* r2_w   = (const float*)d_in[10];
  const float* r2_b   = (const float*)d_in[11];
  float* out = (float*)d_out;

  char* ws = (char*)d_ws;
  size_t off = 0;
  auto alloc = [&](size_t bytes) -> char* {
    char* p = ws + off;
    off += (bytes + 255) & ~(size_t)255;
    return p;
  };
  unsigned short* hb  = (unsigned short*)alloc((size_t)N_NODESC * HIDC * 2);  // 25.6 MB
  unsigned short* ab  = (unsigned short*)alloc((size_t)N_NODESC * HIDC * 2);  // 25.6 MB
  unsigned short* MTP = (unsigned short*)alloc((size_t)32768 * 2);            // 64 KB
  unsigned short* EWP = (unsigned short*)alloc((size_t)8192 * 2);             // 16 KB
  int* rowptr   = (int*)alloc((size_t)(N_NODESC + 1) * 4);
  int* colidx   = (int*)alloc((size_t)N_EDGESC * 4);                // 6.4 MB
  unsigned int* ebuf = (unsigned int*)alloc((size_t)N_EDGESC * 4);  // 6.4 MB
  int* histg    = (int*)alloc((size_t)NHIST * 4);
  int* hoff     = (int*)alloc((size_t)NHIST * 4);
  int* bsum     = (int*)alloc((size_t)S1NB * 4);
  int* boff     = (int*)alloc((size_t)S1NB * 4);
  float* part   = (float*)alloc((size_t)N_GRAPHSC * POOL_CHUNKS * 256 * 4);
  float* pool   = (float*)alloc((size_t)N_GRAPHSC * 3 * HIDC * 4);
  float* g1buf  = (float*)alloc((size_t)N_GRAPHSC * 192 * 4);
  (void)ws_size; (void)in_sizes; (void)n_in; (void)out_size;

  const int* srcv = ei;
  const int* dstv = ei + N_EDGESC;

  k_weights_pack<<<128, 256, 0, stream>>>(W, lin_w, MTP);
  k_ew_pack<<<32, 256, 0, stream>>>(emb_w, EWP);
  k_embed_mfma<<<UPD_NB, 256, 0, stream>>>(x, EWP, emb_b, hb);
  k_hist<<<NBLK, 256, 0, stream>>>(dstv, histg);
  k_s1<<<S1NB, 256, 0, stream>>>(histg, bsum);
  k_s2<<<1, 256, 0, stream>>>(bsum, boff);
  k_s3<<<S1NB, 256, 0, stream>>>(histg, boff, hoff);
  k_scatter<<<NBLK, 256, 0, stream>>>(srcv, dstv, hoff, ebuf);
  k_csr<<<NBUK, 256, 0, stream>>>(ebuf, hoff, rowptr, colidx);
  for (int it = 0; it < NUM_ITERSC; ++it) {
    k_gather_b<<<N_NODESC / 4, 256, 0, stream>>>((const unsigned int*)hb, rowptr, colidx,
                                                 (unsigned int*)ab);
    k_update_mfma<<<UPD_NB, 256, 0, stream>>>(hb, ab, MTP, asym_b);
  }
  k_pool1<<<N_GRAPHSC * POOL_CHUNKS, 128, 0, stream>>>(hb, batch, part);
  k_pool2<<<N_GRAPHSC, 128, 0, stream>>>(part, batch, pool);
  k_mlp1<<<N_GRAPHSC, 192, 0, stream>>>(pool, r1_w, r1_b, g1buf);
  k_mlp2<<<(N_GRAPHSC * OUT_DIMC + 255) / 256, 256, 0, stream>>>(g1buf, r2_w, r2_b, out);
}